// Round 14
// baseline (22.483 us; speedup 1.0000x reference)
//
#include <hip/hip_runtime.h>

// Ray-AABB nearest intersection. R rays x B boxes. 2 lanes per ray (even: boxes
// 0..15, odd: 16..31), combined via shfl_xor with strict-< (np.argmin first-min).
//
// Bit-exactness (validated absmax 0.0 R4-R13): Markstein div == RN div given
// exact y=RN(1/rd); separate mul/add roundings for p=ro+t*rd; own-axis band
// check elided; best init = BIG; med3 in-band (finite ordered operands).
// v_pk_* ops are elementwise IEEE RN == the scalar ops they replace; negation
// is exact, so pk_add(bnd, -ro) == sub, pk_fma(-rd, q0, d2) == Markstein resid.
//
// Perf history: R11 probe: VGPR=24, VALUBusy 71-75% (issue-bound on SCALAR VALU),
// bank conflict fixed in R13 (interleaved slots). R7==R8 flatness => ext_vector
// float2 arithmetic SCALARIZED (backend doesn't emit v_pk_*_f32 from <2 x float>).
// This round: force VOP3P dual-issue via inline asm on the division chains, where
// {lo,hi} operands are naturally even-aligned pairs from ds_read_b128 (zero
// packing movs). Per-ray constants duplicated into {v,v} pairs once. 24 scalar ->
// 12 pk ops/box. Block back to 256 (R13's 1024 had 2 WGs/CU, no tail slack).

typedef float v2f __attribute__((ext_vector_type(2)));

constexpr int BMAX = 32;
constexpr int HALF = BMAX / 2;

__device__ __forceinline__ v2f pk_add(v2f a, v2f b) {
    v2f d;
    asm("v_pk_add_f32 %0, %1, %2" : "=v"(d) : "v"(a), "v"(b));
    return d;
}
__device__ __forceinline__ v2f pk_mul(v2f a, v2f b) {
    v2f d;
    asm("v_pk_mul_f32 %0, %1, %2" : "=v"(d) : "v"(a), "v"(b));
    return d;
}
__device__ __forceinline__ v2f pk_fma(v2f a, v2f b, v2f c) {
    v2f d;
    asm("v_pk_fma_f32 %0, %1, %2, %3" : "=v"(d) : "v"(a), "v"(b), "v"(c));
    return d;
}

__global__ __launch_bounds__(256) void ray_aabb_kernel(
    const float* __restrict__ rays_o,
    const float* __restrict__ rays_d,
    const float* __restrict__ bbox,
    float* __restrict__ out_idx,
    float* __restrict__ out_dist,
    int R)
{
    const float BIG = 10000000000.0f;
    const float EPS = 1e-4f;

    // slot(b) = (b&15)*2 + (b>>4): pair-partner (even/odd lane) addresses differ
    // by 48B (disjoint bank quads) instead of 768B (same banks, 2x serialize).
    // Per slot: q0=(lo0,hi0,lo1,hi1)  q1=(lo2,hi2,loE0,loE1)  q2=(loE2,hiE0,hiE1,hiE2)
    __shared__ float4 s_q[BMAX][3];

    int t = threadIdx.x;
    if (t < BMAX) {
        int b = t;
        int slot = (b & 15) * 2 + (b >> 4);
        float lo[3], hi[3], loE[3], hiE[3];
        #pragma unroll
        for (int a = 0; a < 3; ++a) {
            float c = bbox[b * 6 + a];
            float s = bbox[b * 6 + 3 + a];
            float h  = __fmul_rn(s, 0.5f);
            lo[a]  = __fsub_rn(c, h);
            hi[a]  = __fadd_rn(c, h);
            loE[a] = __fsub_rn(lo[a], EPS);
            hiE[a] = __fadd_rn(hi[a], EPS);
        }
        s_q[slot][0] = make_float4(lo[0], hi[0], lo[1], hi[1]);
        s_q[slot][1] = make_float4(lo[2], hi[2], loE[0], loE[1]);
        s_q[slot][2] = make_float4(loE[2], hiE[0], hiE[1], hiE[2]);
    }
    __syncthreads();

    // 2 threads per ray: parity selects box half.
    int gid  = blockIdx.x * blockDim.x + threadIdx.x;
    int ray  = gid >> 1;
    int par  = gid & 1;          // 0: boxes [0,16)  1: boxes [16,32)
    if (ray >= R) return;
    int b0   = par * HALF;

    float ro[3], rd[3], y[3];
    v2f y2[3], nro2[3], nrd2[3];     // duplicated per-ray constants for pk ops
    #pragma unroll
    for (int a = 0; a < 3; ++a) {
        ro[a] = rays_o[ray * 3 + a];
        float d = rays_d[ray * 3 + a];
        rd[a] = (d == 0.0f) ? 1e-8f : d;
        y[a]  = __fdiv_rn(1.0f, rd[a]);   // exact RN reciprocal (Markstein precondition)
        y2[a]   = v2f{y[a], y[a]};
        nro2[a] = v2f{-ro[a], -ro[a]};    // negation exact
        nrd2[a] = v2f{-rd[a], -rd[a]};
    }

    bool  keep  = false;
    float best  = BIG;   // all-invalid half => (BIG, b0); matches np argmin-of-all-BIG
    int   bestb = b0;

    #pragma unroll 4
    for (int bi = 0; bi < HALF; ++bi) {
        int slot = bi * 2 + par;
        int b    = b0 + bi;            // true box index
        float4 q0 = s_q[slot][0];
        float4 q1 = s_q[slot][1];
        float4 q2 = s_q[slot][2];
        v2f bnd[3];                    // {lo,hi} per axis: even-aligned pairs from b128
        bnd[0] = v2f{q0.x, q0.y};
        bnd[1] = v2f{q0.z, q0.w};
        bnd[2] = v2f{q1.x, q1.y};
        float loE[3] = {q1.z, q1.w, q2.x};
        float hiE[3] = {q2.y, q2.z, q2.w};

        float entry[3], exitv[3];
        #pragma unroll
        for (int a = 0; a < 3; ++a) {
            // Packed Markstein (forced VOP3P): both bounds' divisions per axis.
            v2f d2  = pk_add(bnd[a], nro2[a]);        // bnd - ro   (exact neg)
            v2f q0v = pk_mul(d2, y2[a]);              // RN(d2*y)
            v2f e   = pk_fma(nrd2[a], q0v, d2);       // exact residual d2 - rd*q0
            v2f qv  = pk_fma(e, y2[a], q0v);          // == RN(d2/rd)
            entry[a] = fminf(qv.x, qv.y);
            exitv[a] = fmaxf(qv.x, qv.y);
        }
        float tmm = fmaxf(entry[0], fmaxf(entry[1], entry[2]));
        float tmx = fminf(exitv[0], fminf(exitv[1], exitv[2]));
        keep = keep || ((tmm < tmx) && (tmx > 0.0f));

        // In-band via v_med3_f32: for axis a, candidates from the two OTHER axes.
        // Scalar on purpose: packing entry[o1],entry[o2] would cost 2 movs = the gain.
        bool inb[3][3];
        #pragma unroll
        for (int a = 0; a < 3; ++a) {
            int o1 = (a == 0) ? 1 : 0;
            int o2 = (a == 2) ? 1 : 2;
            float m1 = __fmul_rn(entry[o1], rd[a]);   // mul rounded
            float m2 = __fmul_rn(entry[o2], rd[a]);
            float p1 = __fadd_rn(ro[a], m1);          // add rounded (no contraction)
            float p2 = __fadd_rn(ro[a], m2);
            inb[a][o1] = (__builtin_amdgcn_fmed3f(p1, loE[a], hiE[a]) == p1);
            inb[a][o2] = (__builtin_amdgcn_fmed3f(p2, loE[a], hiE[a]) == p2);
        }
        float tn = BIG;
        #pragma unroll
        for (int cnd = 0; cnd < 3; ++cnd) {
            int a1 = (cnd == 0) ? 1 : 0;
            int a2 = (cnd == 2) ? 1 : 2;
            bool v = (entry[cnd] >= 0.0f) && inb[a1][cnd] && inb[a2][cnd];
            if (v) tn = fminf(tn, entry[cnd]);
        }
        if (tn < best) { best = tn; bestb = b; }  // strict <: first-min within half
    }

    // Pair combine: odd lane's half (boxes 16..31) wins only on STRICT < .
    float o_best  = __shfl_xor(best, 1, 64);
    int   o_bestb = __shfl_xor(bestb, 1, 64);
    int   o_keep  = __shfl_xor((int)keep, 1, 64);

    if (par == 0) {
        bool k = keep || (o_keep != 0);
        float fb = best; int fi = bestb;
        if (o_best < fb) { fb = o_best; fi = o_bestb; }   // hi half only if strictly smaller
        out_idx[ray]  = k ? (float)fi : -1.0f;
        out_dist[ray] = k ? fb : -1.0f;
    }
}

extern "C" void kernel_launch(void* const* d_in, const int* in_sizes, int n_in,
                              void* d_out, int out_size, void* d_ws, size_t ws_size,
                              hipStream_t stream) {
    const float* rays_o = (const float*)d_in[0];
    const float* rays_d = (const float*)d_in[1];
    const float* bbox   = (const float*)d_in[2];
    int R = in_sizes[0] / 3;

    float* out = (float*)d_out;
    float* out_idx  = out;
    float* out_dist = out + R;

    const int threads = 256;    // 2048 WGs -> 8/CU, good tail slack (R13 lesson)
    const long long total = 2LL * R;                 // 2 threads per ray
    const int blocks = (int)((total + threads - 1) / threads);
    ray_aabb_kernel<<<blocks, threads, 0, stream>>>(rays_o, rays_d, bbox,
                                                    out_idx, out_dist, R);
}

// Round 15
// 20.593 us; speedup vs baseline: 1.0918x; 1.0918x over previous
//
#include <hip/hip_runtime.h>

// Ray-AABB nearest intersection. R rays x B boxes. 2 lanes per ray (even: boxes
// 0..15, odd: 16..31), combined via shfl_xor with strict-< (np.argmin first-min).
//
// Bit-exactness (validated absmax 0.0 R4-R14): Markstein div == RN div given
// exact y=RN(1/rd); separate mul/add roundings for p=ro+t*rd; own-axis band
// check elided; best init = BIG; med3 in-band (finite ordered operands).
//
// Perf facts accumulated: VGPR=24, VALUBusy 71-75% -> issue-bound on scalar VALU.
// v_pk_*_f32 does NOT double f32 rate on CDNA4 (R14 flat; 157.3TF spec == scalar
// rate) -> scalar body. LDS bank conflicts fixed via pair-interleaved slots (R13).
// This round: (a) tn computed as select-to-BIG + fmin tree so clang fuses
// v_min3_f32 (the guarded if(v) form blocked fusion); (b) unroll 8 for deeper
// LDS-read hoisting (lgkmcnt stalls are part of the 27% non-issue cycles).

constexpr int BMAX = 32;
constexpr int HALF = BMAX / 2;

__device__ __forceinline__ float div_markstein(float a, float b, float y) {
    float q0 = __fmul_rn(a, y);
    float e  = __fmaf_rn(-b, q0, a);   // exact residual
    return __fmaf_rn(e, y, q0);        // == __fdiv_rn(a, b)
}

__global__ __launch_bounds__(256) void ray_aabb_kernel(
    const float* __restrict__ rays_o,
    const float* __restrict__ rays_d,
    const float* __restrict__ bbox,
    float* __restrict__ out_idx,
    float* __restrict__ out_dist,
    int R)
{
    const float BIG = 10000000000.0f;
    const float EPS = 1e-4f;

    // slot(b) = (b&15)*2 + (b>>4): pair-partner (even/odd lane) broadcast addrs
    // differ by 48B (disjoint bank quads) instead of 768B (same banks, 2x serial).
    // Per slot: q0=(lo0,hi0,lo1,hi1)  q1=(lo2,hi2,loE0,loE1)  q2=(loE2,hiE0,hiE1,hiE2)
    __shared__ float4 s_q[BMAX][3];

    int t = threadIdx.x;
    if (t < BMAX) {
        int b = t;
        int slot = (b & 15) * 2 + (b >> 4);
        float lo[3], hi[3], loE[3], hiE[3];
        #pragma unroll
        for (int a = 0; a < 3; ++a) {
            float c = bbox[b * 6 + a];
            float s = bbox[b * 6 + 3 + a];
            float h  = __fmul_rn(s, 0.5f);
            lo[a]  = __fsub_rn(c, h);
            hi[a]  = __fadd_rn(c, h);
            loE[a] = __fsub_rn(lo[a], EPS);
            hiE[a] = __fadd_rn(hi[a], EPS);
        }
        s_q[slot][0] = make_float4(lo[0], hi[0], lo[1], hi[1]);
        s_q[slot][1] = make_float4(lo[2], hi[2], loE[0], loE[1]);
        s_q[slot][2] = make_float4(loE[2], hiE[0], hiE[1], hiE[2]);
    }
    __syncthreads();

    // 2 threads per ray: parity selects box half.
    int gid  = blockIdx.x * blockDim.x + threadIdx.x;
    int ray  = gid >> 1;
    int par  = gid & 1;          // 0: boxes [0,16)  1: boxes [16,32)
    if (ray >= R) return;
    int b0   = par * HALF;

    float ro[3], rd[3], y[3];
    #pragma unroll
    for (int a = 0; a < 3; ++a) {
        ro[a] = rays_o[ray * 3 + a];
        float d = rays_d[ray * 3 + a];
        rd[a] = (d == 0.0f) ? 1e-8f : d;
        y[a]  = __fdiv_rn(1.0f, rd[a]);   // exact RN reciprocal (Markstein precondition)
    }

    bool  keep  = false;
    float best  = BIG;   // all-invalid half => (BIG, b0); matches np argmin-of-all-BIG
    int   bestb = b0;

    #pragma unroll 8
    for (int bi = 0; bi < HALF; ++bi) {
        int slot = bi * 2 + par;
        int b    = b0 + bi;            // true box index
        float4 q0 = s_q[slot][0];
        float4 q1 = s_q[slot][1];
        float4 q2 = s_q[slot][2];
        float lo[3]  = {q0.x, q0.z, q1.x};
        float hi[3]  = {q0.y, q0.w, q1.y};
        float loE[3] = {q1.z, q1.w, q2.x};
        float hiE[3] = {q2.y, q2.z, q2.w};

        float entry[3], exitv[3];
        #pragma unroll
        for (int a = 0; a < 3; ++a) {
            float t1 = div_markstein(__fsub_rn(lo[a], ro[a]), rd[a], y[a]);
            float t2 = div_markstein(__fsub_rn(hi[a], ro[a]), rd[a], y[a]);
            entry[a] = fminf(t1, t2);
            exitv[a] = fmaxf(t1, t2);
        }
        // fmax/fmin trees fuse to v_max3_f32 / v_min3_f32.
        float tmm = fmaxf(entry[0], fmaxf(entry[1], entry[2]));
        float tmx = fminf(exitv[0], fminf(exitv[1], exitv[2]));
        keep = keep || ((tmm < tmx) && (tmx > 0.0f));

        // In-band via v_med3_f32 on the two OTHER axes per candidate.
        bool inb[3][3];
        #pragma unroll
        for (int a = 0; a < 3; ++a) {
            int o1 = (a == 0) ? 1 : 0;
            int o2 = (a == 2) ? 1 : 2;
            float m1 = __fmul_rn(entry[o1], rd[a]);   // mul rounded
            float m2 = __fmul_rn(entry[o2], rd[a]);
            float p1 = __fadd_rn(ro[a], m1);          // add rounded (no contraction)
            float p2 = __fadd_rn(ro[a], m2);
            inb[a][o1] = (__builtin_amdgcn_fmed3f(p1, loE[a], hiE[a]) == p1);
            inb[a][o2] = (__builtin_amdgcn_fmed3f(p2, loE[a], hiE[a]) == p2);
        }
        // Select-to-BIG then a min tree -> v_min3_f32 fusable (guarded-min blocked it).
        float tsel[3];
        #pragma unroll
        for (int cnd = 0; cnd < 3; ++cnd) {
            int a1 = (cnd == 0) ? 1 : 0;
            int a2 = (cnd == 2) ? 1 : 2;
            bool v = (entry[cnd] >= 0.0f) && inb[a1][cnd] && inb[a2][cnd];
            tsel[cnd] = v ? entry[cnd] : BIG;
        }
        float tn = fminf(tsel[0], fminf(tsel[1], tsel[2]));
        if (tn < best) { best = tn; bestb = b; }  // strict <: first-min within half
    }

    // Pair combine: odd lane's half (boxes 16..31) wins only on STRICT < .
    float o_best  = __shfl_xor(best, 1, 64);
    int   o_bestb = __shfl_xor(bestb, 1, 64);
    int   o_keep  = __shfl_xor((int)keep, 1, 64);

    if (par == 0) {
        bool k = keep || (o_keep != 0);
        float fb = best; int fi = bestb;
        if (o_best < fb) { fb = o_best; fi = o_bestb; }   // hi half only if strictly smaller
        out_idx[ray]  = k ? (float)fi : -1.0f;
        out_dist[ray] = k ? fb : -1.0f;
    }
}

extern "C" void kernel_launch(void* const* d_in, const int* in_sizes, int n_in,
                              void* d_out, int out_size, void* d_ws, size_t ws_size,
                              hipStream_t stream) {
    const float* rays_o = (const float*)d_in[0];
    const float* rays_d = (const float*)d_in[1];
    const float* bbox   = (const float*)d_in[2];
    int R = in_sizes[0] / 3;

    float* out = (float*)d_out;
    float* out_idx  = out;
    float* out_dist = out + R;

    const int threads = 256;
    const long long total = 2LL * R;                 // 2 threads per ray
    const int blocks = (int)((total + threads - 1) / threads);
    ray_aabb_kernel<<<blocks, threads, 0, stream>>>(rays_o, rays_d, bbox,
                                                    out_idx, out_dist, R);
}